// Round 13
// baseline (1046.779 us; speedup 1.0000x reference)
//
#include <hip/hip_runtime.h>
#include <hip/hip_bf16.h>
#include <math.h>

// PointNet++ SAModule: FPS -> ball query -> PointNetConv(MLP, max-agg)
// B=16, N=4096, S=1024, K=64, r=0.1, MLP 67->64->64->128.
// R13: producer widened to 512 thr / 8 waves (2 waves/SIMD, 8 pts/lane):
// halves per-wave issue and lets paired waves hide each other's dependency
// bubbles (R8-measured mechanism) -- attacks the measured ~1085cy/step stall.
// Selection exact: per-point md math identical; packed-key argmax is
// partition-invariant. Consumers: 4-wave logic inside 512-thr blocks; waves
// 4-7 idle through compute but hit every barrier.

#define NB 16
#define NP 4096
#define FIN 64
#define NS 1024
#define KN 64
#define CAP 128
#define NCONS 240
#define NCHUNK 4096

typedef __attribute__((ext_vector_type(8))) short bf16x8;
typedef __attribute__((ext_vector_type(4))) float f32x4;

__device__ __forceinline__ float dist2e(float ax, float ay, float az,
                                        float bx, float by, float bz) {
    float dx = __fsub_rn(ax, bx);
    float dy = __fsub_rn(ay, by);
    float dz = __fsub_rn(az, bz);
    return __fadd_rn(__fadd_rn(__fmul_rn(dx, dx), __fmul_rn(dy, dy)),
                     __fmul_rn(dz, dz));
}

__device__ __forceinline__ short f2bf(float f) {  // RNE fp32 -> bf16 bits
    unsigned u = __float_as_uint(f);
    unsigned r = (u + 0x7FFFu + ((u >> 16) & 1u)) >> 16;
    return (short)r;
}

#define DPP_KEY_MAX(k, CTRL)                                                   \
    do {                                                                       \
        int _lo = (int)(unsigned)((k) & 0xFFFFFFFFull);                        \
        int _hi = (int)(unsigned)((k) >> 32);                                  \
        int _plo = __builtin_amdgcn_update_dpp(_lo, _lo, CTRL, 0xF, 0xF, false);\
        int _phi = __builtin_amdgcn_update_dpp(_hi, _hi, CTRL, 0xF, 0xF, false);\
        unsigned long long _nk =                                               \
            ((unsigned long long)(unsigned)_phi << 32) | (unsigned)_plo;       \
        if (_nk > (k)) (k) = _nk;                                              \
    } while (0)

#define SMEM_BYTES 27648

__global__ __launch_bounds__(512, 1) void fused_kernel(
        const float* __restrict__ pos, const float* __restrict__ x,
        const float* __restrict__ W1, const float* __restrict__ b1,
        const float* __restrict__ W2, const float* __restrict__ b2,
        const float* __restrict__ W3, const float* __restrict__ b3,
        float* __restrict__ out_feat, float* __restrict__ out_pos,
        float* __restrict__ out_batch, float* __restrict__ histg,
        int* __restrict__ progress) {
    __shared__ __align__(16) char smem[SMEM_BYTES];
    const int tid = threadIdx.x;
    const int lane = tid & 63;
    const int wv = tid >> 6;          // 0..7

    if (blockIdx.x < NB) {
        // =================== FPS producer: 8 waves, 8 pts/lane ==============
        const int b = blockIdx.x;
        float4* hist = (float4*)smem;                       // [1024] 16KB
        float (*bc)[8][8] = (float(*)[8][8])(smem + 16384); // [2][8][8]
        const float* p = pos + (size_t)b * NP * 3;
        float lx[8], ly[8], lz[8], md[8];
#pragma unroll
        for (int i = 0; i < 8; ++i) {
            int j = tid + (i << 9);
            lx[i] = p[j * 3 + 0];
            ly[i] = p[j * 3 + 1];
            lz[i] = p[j * 3 + 2];
            md[i] = INFINITY;
        }
#pragma unroll
        for (int i = 0; i < 8; ++i) {
            asm volatile("" : "+v"(lx[i]), "+v"(ly[i]), "+v"(lz[i]));
        }
        const float c0x = p[0], c0y = p[1], c0z = p[2];
        float cx = c0x, cy = c0y, cz = c0z;
        if (tid == 0) hist[0] = make_float4(0.f, c0x, c0y, c0z);
        for (int s = 1; s < NS; ++s) {
            float bv = -1.0f;
            int bi = 0;
            float wx = 0.f, wy = 0.f, wz = 0.f;
#pragma unroll
            for (int i = 0; i < 8; ++i) {
                float d = dist2e(lx[i], ly[i], lz[i], cx, cy, cz);
                float m = md[i];
                m = d < m ? d : m;   // jnp.minimum (exact)
                md[i] = m;
                bool take = (m > bv);   // strict >, asc i => lowest j on tie
                bv = take ? m : bv;
                bi = take ? (tid + (i << 9)) : bi;
                wx = take ? lx[i] : wx;
                wy = take ? ly[i] : wy;
                wz = take ? lz[i] : wz;
            }
            // pack: positive-f32 bits order-isomorphic; ~idx => tie->lower idx
            unsigned long long key =
                ((unsigned long long)__float_as_uint(bv) << 32) |
                (unsigned)(~(unsigned)bi);
            const unsigned long long my = key;
            DPP_KEY_MAX(key, 0x111);
            DPP_KEY_MAX(key, 0x112);
            DPP_KEY_MAX(key, 0x114);
            DPP_KEY_MAX(key, 0x118);
            DPP_KEY_MAX(key, 0x142);
            DPP_KEY_MAX(key, 0x143);
            const unsigned kwlo = (unsigned)__builtin_amdgcn_readlane(
                (int)(unsigned)(key & 0xFFFFFFFFull), 63);
            const unsigned kwhi = (unsigned)__builtin_amdgcn_readlane(
                (int)(unsigned)(key >> 32), 63);
            const unsigned long long kw =
                ((unsigned long long)kwhi << 32) | kwlo;
            const int buf = s & 1;
            if (my == kw) {            // unique winner lane per wave
                bc[buf][wv][0] = __uint_as_float(kwlo);
                bc[buf][wv][1] = __uint_as_float(kwhi);
                bc[buf][wv][2] = wx;
                bc[buf][wv][3] = wy;
                bc[buf][wv][4] = wz;
            }
            __syncthreads();
            if ((s & 63) == 0) {   // publish centers [s-64, s)
                const int base = s - 64;
                if (tid < 192) {
                    int cc = tid / 3, comp = tid % 3;
                    float4 h = hist[base + cc];
                    float v = comp == 0 ? h.y : (comp == 1 ? h.z : h.w);
                    __hip_atomic_store(
                        (unsigned*)&histg[((size_t)(b * NS + base + cc)) * 3 + comp],
                        __float_as_uint(v), __ATOMIC_RELAXED,
                        __HIP_MEMORY_SCOPE_AGENT);
                }
                __syncthreads();
                if (tid == 0)
                    __hip_atomic_store(&progress[b << 5], s, __ATOMIC_RELEASE,
                                       __HIP_MEMORY_SCOPE_AGENT);
            }
            // select best of the 8 wave candidates
            unsigned long long bk;
            float bx, by, bz;
            {
                float4 e = *(const float4*)&bc[buf][0][0];
                bk = ((unsigned long long)__float_as_uint(e.y) << 32) |
                     __float_as_uint(e.x);
                bx = e.z; by = e.w; bz = bc[buf][0][4];
            }
#pragma unroll
            for (int w = 1; w < 8; ++w) {
                float4 e = *(const float4*)&bc[buf][w][0];
                unsigned long long k2 =
                    ((unsigned long long)__float_as_uint(e.y) << 32) |
                    __float_as_uint(e.x);
                float z2 = bc[buf][w][4];
                bool take = (k2 > bk);
                bk = take ? k2 : bk;
                bx = take ? e.z : bx;
                by = take ? e.w : by;
                bz = take ? z2 : bz;
            }
            const int cur = (int)(~(unsigned)(bk & 0xFFFFFFFFull));
            cx = bx; cy = by; cz = bz;
            if (tid == 0)
                hist[s] = make_float4(__int_as_float(cur), bx, by, bz);
        }
        __syncthreads();
        // final publish [960,1024) + output drain
        if (tid < 192) {
            int cc = tid / 3, comp = tid % 3;
            float4 h = hist[960 + cc];
            float v = comp == 0 ? h.y : (comp == 1 ? h.z : h.w);
            __hip_atomic_store(
                (unsigned*)&histg[((size_t)(b * NS + 960 + cc)) * 3 + comp],
                __float_as_uint(v), __ATOMIC_RELAXED, __HIP_MEMORY_SCOPE_AGENT);
        }
        __syncthreads();
        if (tid == 0)
            __hip_atomic_store(&progress[b << 5], NS, __ATOMIC_RELEASE,
                               __HIP_MEMORY_SCOPE_AGENT);
        for (int s = tid; s < NS; s += 512) {
            float4 e = hist[s];
            out_pos[(size_t)(b * NS + s) * 3 + 0] = e.y;
            out_pos[(size_t)(b * NS + s) * 3 + 1] = e.z;
            out_pos[(size_t)(b * NS + s) * 3 + 2] = e.w;
            out_batch[b * NS + s] = (float)b;
        }
        return;
    }

    // ============ consumer: waves 0-3 work, waves 4-7 barrier-only ==========
    const int w = blockIdx.x - NB;  // 0..239
    short* h1s = (short*)smem;                      // 8KB
    short* h2s = (short*)(smem + 8192);             // 8KB
    float* cd2 = (float*)(smem + 16384);            // [4][CAP]
    int*   cix = (int*)(smem + 18432);              // [4][CAP]
    float* dpxA = (float*)(smem + 20480);           // [4][64]
    float* dpyA = (float*)(smem + 21504);
    float* dpzA = (float*)(smem + 22528);
    int*   jA   = (int*)(smem + 23552);             // [4][64]
    float* omax = (float*)(smem + 24576);           // [4][128]
    int*   keepW = (int*)(smem + 26624);            // [4]
    const int lg = lane >> 4;
    const int lr = lane & 15;
    const bool act = (wv < 4);
    // ---- W fragments (bf16) into registers (loaded by all waves; harmless) -
    bf16x8 w1f[3][4], w2f[2][4], w3f[2][8];
#pragma unroll
    for (int kt = 0; kt < 3; ++kt)
#pragma unroll
        for (int ct = 0; ct < 4; ++ct) {
            bf16x8 f;
#pragma unroll
            for (int i = 0; i < 8; ++i) {
                int k = 32 * kt + 8 * lg + i;
                float v = (k < 67) ? W1[k * 64 + 16 * ct + lr] : 0.f;
                f[i] = f2bf(v);
            }
            w1f[kt][ct] = f;
        }
#pragma unroll
    for (int kt = 0; kt < 2; ++kt)
#pragma unroll
        for (int ct = 0; ct < 4; ++ct) {
            bf16x8 f;
#pragma unroll
            for (int i = 0; i < 8; ++i) {
                int k = 32 * kt + 8 * lg + i;
                f[i] = f2bf(W2[k * 64 + 16 * ct + lr]);
            }
            w2f[kt][ct] = f;
        }
#pragma unroll
    for (int kt = 0; kt < 2; ++kt)
#pragma unroll
        for (int ct = 0; ct < 8; ++ct) {
            bf16x8 f;
#pragma unroll
            for (int i = 0; i < 8; ++i) {
                int k = 32 * kt + 8 * lg + i;
                f[i] = f2bf(W3[k * 128 + 16 * ct + lr]);
            }
            w3f[kt][ct] = f;
        }
    float b1v[4], b2v[4], b3v[8];
#pragma unroll
    for (int ct = 0; ct < 4; ++ct) {
        b1v[ct] = b1[16 * ct + lr];
        b2v[ct] = b2[16 * ct + lr];
    }
#pragma unroll
    for (int ct = 0; ct < 8; ++ct) b3v[ct] = b3[16 * ct + lr];

    for (int c = w; c < NCHUNK; c += NCONS) {
        const int s = c >> 2;
        const int bq = (c & 3) << 2;
        if (act) {
            const int bw = bq + wv;
            while (__hip_atomic_load(&progress[bw << 5], __ATOMIC_ACQUIRE,
                                     __HIP_MEMORY_SCOPE_AGENT) <= s) {
                __builtin_amdgcn_s_sleep(16);
            }
            const size_t ho = ((size_t)(bw * NS + s)) * 3;
            const float ccx = __uint_as_float(__hip_atomic_load(
                (const unsigned*)&histg[ho + 0], __ATOMIC_RELAXED,
                __HIP_MEMORY_SCOPE_AGENT));
            const float ccy = __uint_as_float(__hip_atomic_load(
                (const unsigned*)&histg[ho + 1], __ATOMIC_RELAXED,
                __HIP_MEMORY_SCOPE_AGENT));
            const float ccz = __uint_as_float(__hip_atomic_load(
                (const unsigned*)&histg[ho + 2], __ATOMIC_RELAXED,
                __HIP_MEMORY_SCOPE_AGENT));
            // ---- per-wave ball query ----
            int cnt = 0;
            const float* pcloud = pos + (size_t)bw * NP * 3;
            for (int it = 0; it < 64; ++it) {
                const int j = it * 64 + lane;
                const float* pp = pcloud + (size_t)j * 3;
                float d2 = dist2e(ccx, ccy, ccz, pp[0], pp[1], pp[2]);
                bool in = (d2 <= 0.01f);  // f32(0.1*0.1)
                unsigned long long m = __ballot(in);
                if (in) {
                    int slot = cnt + __popcll(m & ((1ull << lane) - 1ull));
                    if (slot < CAP) {
                        cd2[wv * CAP + slot] = d2;
                        cix[wv * CAP + slot] = j;
                    }
                }
                cnt += __popcll(m);
            }
            if (cnt > CAP) cnt = CAP;
            const int keep = cnt <= KN ? cnt : KN;
            if (lane == 0) keepW[wv] = keep;
            jA[wv * 64 + lane] = 0;
            if (cnt <= KN) {
                if (lane < keep) jA[wv * 64 + lane] = cix[wv * CAP + lane];
            } else {
                // exact K-nearest: (d2, idx) lexicographic rank (top_k order)
                for (int e = lane; e < cnt; e += 64) {
                    float d = cd2[wv * CAP + e];
                    int id = cix[wv * CAP + e];
                    int rank = 0;
                    for (int q = 0; q < cnt; ++q) {
                        float dq = cd2[wv * CAP + q];
                        int iq = cix[wv * CAP + q];
                        rank += (dq < d || (dq == d && iq < id)) ? 1 : 0;
                    }
                    if (rank < KN) jA[wv * 64 + rank] = id;
                }
            }
            {
                int j = jA[wv * 64 + lane];
                const float* pp = pcloud + (size_t)j * 3;
                bool valid = lane < keep;
                dpxA[wv * 64 + lane] = valid ? (pp[0] - ccx) : 0.f;
                dpyA[wv * 64 + lane] = valid ? (pp[1] - ccy) : 0.f;
                dpzA[wv * 64 + lane] = valid ? (pp[2] - ccz) : 0.f;
            }
        }
        __syncthreads();
        // ---- conv for the 4 centers (waves 0-3; barriers hit by all) ----
        for (int cc = 0; cc < 4; ++cc) {
            if (act) {
                const int C = keepW[cc];
                const int arow = 16 * wv + lr;
                bf16x8 a0, a1, a2;
                {
                    const int jrow = (bq + cc) * NP + jA[cc * 64 + arow];
                    const float* xr = x + (size_t)jrow * FIN + 8 * lg;
                    float4 v0 = *(const float4*)(xr + 0);
                    float4 v1 = *(const float4*)(xr + 4);
                    float4 v2 = *(const float4*)(xr + 32);
                    float4 v3 = *(const float4*)(xr + 36);
                    a0[0] = f2bf(v0.x); a0[1] = f2bf(v0.y); a0[2] = f2bf(v0.z); a0[3] = f2bf(v0.w);
                    a0[4] = f2bf(v1.x); a0[5] = f2bf(v1.y); a0[6] = f2bf(v1.z); a0[7] = f2bf(v1.w);
                    a1[0] = f2bf(v2.x); a1[1] = f2bf(v2.y); a1[2] = f2bf(v2.z); a1[3] = f2bf(v2.w);
                    a1[4] = f2bf(v3.x); a1[5] = f2bf(v3.y); a1[6] = f2bf(v3.z); a1[7] = f2bf(v3.w);
                    float d0 = (lg == 0) ? dpxA[cc * 64 + arow] : 0.f;
                    float d1 = (lg == 0) ? dpyA[cc * 64 + arow] : 0.f;
                    float d2v = (lg == 0) ? dpzA[cc * 64 + arow] : 0.f;
                    a2[0] = f2bf(d0); a2[1] = f2bf(d1); a2[2] = f2bf(d2v);
                    a2[3] = 0; a2[4] = 0; a2[5] = 0; a2[6] = 0; a2[7] = 0;
                }
                {
                    f32x4 acc[4];
#pragma unroll
                    for (int ct = 0; ct < 4; ++ct) {
                        acc[ct] = (f32x4){b1v[ct], b1v[ct], b1v[ct], b1v[ct]};
                        acc[ct] = __builtin_amdgcn_mfma_f32_16x16x32_bf16(a0, w1f[0][ct], acc[ct], 0, 0, 0);
                        acc[ct] = __builtin_amdgcn_mfma_f32_16x16x32_bf16(a1, w1f[1][ct], acc[ct], 0, 0, 0);
                        acc[ct] = __builtin_amdgcn_mfma_f32_16x16x32_bf16(a2, w1f[2][ct], acc[ct], 0, 0, 0);
                    }
#pragma unroll
                    for (int ct = 0; ct < 4; ++ct)
#pragma unroll
                        for (int r = 0; r < 4; ++r) {
                            int rw = 16 * wv + 4 * lg + r;
                            int idx = rw * 64 + 16 * ct + lr;
                            h1s[idx ^ ((rw & 7) << 3)] = f2bf(fmaxf(acc[ct][r], 0.f));
                        }
                }
                bf16x8 ha0 = *(bf16x8*)&h1s[(arow * 64 + 0  + 8 * lg) ^ ((arow & 7) << 3)];
                bf16x8 ha1 = *(bf16x8*)&h1s[(arow * 64 + 32 + 8 * lg) ^ ((arow & 7) << 3)];
                {
                    f32x4 acc[4];
#pragma unroll
                    for (int ct = 0; ct < 4; ++ct) {
                        acc[ct] = (f32x4){b2v[ct], b2v[ct], b2v[ct], b2v[ct]};
                        acc[ct] = __builtin_amdgcn_mfma_f32_16x16x32_bf16(ha0, w2f[0][ct], acc[ct], 0, 0, 0);
                        acc[ct] = __builtin_amdgcn_mfma_f32_16x16x32_bf16(ha1, w2f[1][ct], acc[ct], 0, 0, 0);
                    }
#pragma unroll
                    for (int ct = 0; ct < 4; ++ct)
#pragma unroll
                        for (int r = 0; r < 4; ++r) {
                            int rw = 16 * wv + 4 * lg + r;
                            int idx = rw * 64 + 16 * ct + lr;
                            h2s[idx ^ ((rw & 7) << 3)] = f2bf(fmaxf(acc[ct][r], 0.f));
                        }
                }
                bf16x8 hb0 = *(bf16x8*)&h2s[(arow * 64 + 0  + 8 * lg) ^ ((arow & 7) << 3)];
                bf16x8 hb1 = *(bf16x8*)&h2s[(arow * 64 + 32 + 8 * lg) ^ ((arow & 7) << 3)];
                {
                    f32x4 acc3[8];
#pragma unroll
                    for (int ct = 0; ct < 8; ++ct) {
                        acc3[ct] = (f32x4){b3v[ct], b3v[ct], b3v[ct], b3v[ct]};
                        acc3[ct] = __builtin_amdgcn_mfma_f32_16x16x32_bf16(hb0, w3f[0][ct], acc3[ct], 0, 0, 0);
                        acc3[ct] = __builtin_amdgcn_mfma_f32_16x16x32_bf16(hb1, w3f[1][ct], acc3[ct], 0, 0, 0);
                    }
#pragma unroll
                    for (int ct = 0; ct < 8; ++ct) {
                        float m = -INFINITY;
#pragma unroll
                        for (int r = 0; r < 4; ++r) {
                            int rg = 16 * wv + 4 * lg + r;
                            float v = fmaxf(acc3[ct][r], 0.f);
                            m = (rg < C && v > m) ? v : m;
                        }
                        m = fmaxf(m, __shfl_xor(m, 16, 64));
                        m = fmaxf(m, __shfl_xor(m, 32, 64));
                        if (lg == 0) omax[wv * 128 + 16 * ct + lr] = m;
                    }
                }
            }
            __syncthreads();
            if (tid < 128) {
                const int cen = (bq + cc) * NS + s;
                float m = fmaxf(fmaxf(omax[0 * 128 + tid], omax[1 * 128 + tid]),
                                fmaxf(omax[2 * 128 + tid], omax[3 * 128 + tid]));
                out_feat[(size_t)cen * 128 + tid] = m;
            }
            __syncthreads();
        }
    }
}

extern "C" void kernel_launch(void* const* d_in, const int* in_sizes, int n_in,
                              void* d_out, int out_size, void* d_ws, size_t ws_size,
                              hipStream_t stream) {
    const float* x   = (const float*)d_in[0];
    const float* pos = (const float*)d_in[1];
    const float* W1  = (const float*)d_in[3];
    const float* b1  = (const float*)d_in[4];
    const float* W2  = (const float*)d_in[5];
    const float* b2  = (const float*)d_in[6];
    const float* W3  = (const float*)d_in[7];
    const float* b3  = (const float*)d_in[8];
    float* out = (float*)d_out;
    char* ws = (char*)d_ws;
    int*   progress = (int*)ws;                    // 16 x 128B padded slots
    float* histg    = (float*)(ws + 4096);         // [16][1024][3] = 192KB
    float* out_feat  = out;                        // [16384][128]
    float* out_pos   = out + (size_t)16384 * 128;  // [16384][3]
    float* out_batch = out + (size_t)16384 * 131;  // [16384]
    hipMemsetAsync(ws, 0, 4096, stream);
    fused_kernel<<<256, 512, 0, stream>>>(pos, x, W1, b1, W2, b2, W3, b3,
                                          out_feat, out_pos, out_batch,
                                          histg, progress);
}

// Round 16
// 1009.283 us; speedup vs baseline: 1.0372x; 1.0372x over previous
//
#include <hip/hip_runtime.h>
#include <hip/hip_bf16.h>
#include <math.h>

// PointNet++ SAModule: FPS -> ball query -> PointNetConv(MLP, max-agg)
// B=16, N=4096, S=1024, K=64, r=0.1, MLP 67->64->64->128.
// R14/R15/R16: producer = MEASURED-BEST R5 chain structure (1865 cy/step):
// 4 waves x 16pt/lane, lightest local loop (strict >, no xyz carry),
// 4xDPP row_ror + ds_swizzle(xor16) + shfl_xor(32) reduce, lane0 fetches
// winner xyz from px/py/pz LDS pre-barrier, ONE barrier, 4-way select.
// Fusion infrastructure (publish every 64 steps, padded progress, s_sleep
// spin, MFMA consumers) kept from R12. Selection bit-exact vs numpy.

#define NB 16
#define NP 4096
#define FIN 64
#define NS 1024
#define KN 64
#define CAP 128
#define NCONS 240
#define NCHUNK 4096

typedef __attribute__((ext_vector_type(8))) short bf16x8;
typedef __attribute__((ext_vector_type(4))) float f32x4;

__device__ __forceinline__ float dist2e(float ax, float ay, float az,
                                        float bx, float by, float bz) {
    float dx = __fsub_rn(ax, bx);
    float dy = __fsub_rn(ay, by);
    float dz = __fsub_rn(az, bz);
    return __fadd_rn(__fadd_rn(__fmul_rn(dx, dx), __fmul_rn(dy, dy)),
                     __fmul_rn(dz, dz));
}

__device__ __forceinline__ short f2bf(float f) {  // RNE fp32 -> bf16 bits
    unsigned u = __float_as_uint(f);
    unsigned r = (u + 0x7FFFu + ((u >> 16) & 1u)) >> 16;
    return (short)r;
}

// One DPP row-rotate reduce level on a packed u64 key (max). CTRL literal:
// 0x121=ror:1 0x122=ror:2 0x124=ror:4 0x128=ror:8. (R5-proven, bit-exact.)
#define DPP_KEY_MAX(k, CTRL)                                                   \
    do {                                                                       \
        int _lo = (int)(unsigned)((k) & 0xFFFFFFFFull);                        \
        int _hi = (int)(unsigned)((k) >> 32);                                  \
        int _plo = __builtin_amdgcn_update_dpp(_lo, _lo, CTRL, 0xF, 0xF, false);\
        int _phi = __builtin_amdgcn_update_dpp(_hi, _hi, CTRL, 0xF, 0xF, false);\
        unsigned long long _nk =                                               \
            ((unsigned long long)(unsigned)_phi << 32) | (unsigned)_plo;       \
        if (_nk > (k)) (k) = _nk;                                              \
    } while (0)

// Full wave reduce (max) of packed u64 key: 4 DPP row levels + xor16 + xor32.
#define WAVE_KEY_MAX(k)                                                        \
    do {                                                                       \
        DPP_KEY_MAX(k, 0x121);                                                 \
        DPP_KEY_MAX(k, 0x122);                                                 \
        DPP_KEY_MAX(k, 0x124);                                                 \
        DPP_KEY_MAX(k, 0x128);                                                 \
        {                                                                      \
            int _lo = (int)(unsigned)((k) & 0xFFFFFFFFull);                    \
            int _hi = (int)(unsigned)((k) >> 32);                              \
            int _plo = __builtin_amdgcn_ds_swizzle(_lo, 0x401F);               \
            int _phi = __builtin_amdgcn_ds_swizzle(_hi, 0x401F);               \
            unsigned long long _nk =                                           \
                ((unsigned long long)(unsigned)_phi << 32) | (unsigned)_plo;   \
            if (_nk > (k)) (k) = _nk;                                          \
        }                                                                      \
        {                                                                      \
            unsigned long long _nk = __shfl_xor((k), 32, 64);                  \
            if (_nk > (k)) (k) = _nk;                                          \
        }                                                                      \
    } while (0)

#define SMEM_BYTES 65792

__global__ __launch_bounds__(256, 1) void fused_kernel(
        const float* __restrict__ pos, const float* __restrict__ x,
        const float* __restrict__ W1, const float* __restrict__ b1,
        const float* __restrict__ W2, const float* __restrict__ b2,
        const float* __restrict__ W3, const float* __restrict__ b3,
        float* __restrict__ out_feat, float* __restrict__ out_pos,
        float* __restrict__ out_batch, float* __restrict__ histg,
        int* __restrict__ progress) {
    __shared__ __align__(16) char smem[SMEM_BYTES];
    const int tid = threadIdx.x;
    const int lane = tid & 63;
    const int wv = tid >> 6;

    if (blockIdx.x < NB) {
        // ========== FPS producer: R5 structure + publish (R12 infra) ========
        const int b = blockIdx.x;
        float* px = (float*)smem;                            // [4096] 16KB
        float* py = (float*)(smem + 16384);
        float* pz = (float*)(smem + 32768);
        float4* hist = (float4*)(smem + 49152);              // [1024] 16KB
        float (*bc)[4][8] = (float(*)[4][8])(smem + 65536);  // [2][4][8]
        const float* p = pos + (size_t)b * NP * 3;
        float lx[16], ly[16], lz[16], md[16];
#pragma unroll
        for (int i = 0; i < 16; ++i) {
            int j = tid + (i << 8);
            float xx = p[j * 3 + 0];
            float yy = p[j * 3 + 1];
            float zz = p[j * 3 + 2];
            px[j] = xx; py[j] = yy; pz[j] = zz;
            lx[i] = xx; ly[i] = yy; lz[i] = zz;
            md[i] = INFINITY;
        }
        __syncthreads();
        const float c0x = px[0], c0y = py[0], c0z = pz[0];
        float cx = c0x, cy = c0y, cz = c0z;
        if (tid == 0) hist[0] = make_float4(0.f, c0x, c0y, c0z);
        for (int s = 1; s < NS; ++s) {
            // lightest local loop: strict >, ascending i => lowest idx on tie
            float bv = -1.0f;
            int bi = 0;
#pragma unroll
            for (int i = 0; i < 16; ++i) {
                float d = dist2e(lx[i], ly[i], lz[i], cx, cy, cz);
                float m = md[i];
                m = d < m ? d : m;   // jnp.minimum (exact)
                md[i] = m;
                bool take = (m > bv);
                bv = take ? m : bv;
                bi = take ? (tid + (i << 8)) : bi;
            }
            // pack: positive-f32 bits order-isomorphic; ~idx => tie->lower idx
            unsigned long long key =
                ((unsigned long long)__float_as_uint(bv) << 32) |
                (unsigned)(~(unsigned)bi);
            WAVE_KEY_MAX(key);
            const int buf = s & 1;  // double buffer -> one barrier per step
            if (lane == 0) {
                int wi = (int)(~(unsigned)(key & 0xFFFFFFFFull));
                bc[buf][wv][0] =
                    __uint_as_float((unsigned)(key & 0xFFFFFFFFull));
                bc[buf][wv][1] = __uint_as_float((unsigned)(key >> 32));
                bc[buf][wv][2] = px[wi];
                bc[buf][wv][3] = py[wi];
                bc[buf][wv][4] = pz[wi];
            }
            __syncthreads();
            if ((s & 63) == 0) {   // publish centers [s-64, s)
                const int base = s - 64;
                if (tid < 192) {
                    int cc = tid / 3, comp = tid % 3;
                    float4 h = hist[base + cc];
                    float v = comp == 0 ? h.y : (comp == 1 ? h.z : h.w);
                    __hip_atomic_store(
                        (unsigned*)&histg[((size_t)(b * NS + base + cc)) * 3 + comp],
                        __float_as_uint(v), __ATOMIC_RELAXED,
                        __HIP_MEMORY_SCOPE_AGENT);
                }
                __syncthreads();   // drain stores before release
                if (tid == 0)
                    __hip_atomic_store(&progress[b << 5], s, __ATOMIC_RELEASE,
                                       __HIP_MEMORY_SCOPE_AGENT);
            }
            // all lanes: select best of the 4 wave candidates
            unsigned long long bk;
            float bx, by, bz;
            {
                float4 e = *(const float4*)&bc[buf][0][0];
                bk = ((unsigned long long)__float_as_uint(e.y) << 32) |
                     __float_as_uint(e.x);
                bx = e.z; by = e.w; bz = bc[buf][0][4];
            }
#pragma unroll
            for (int w = 1; w < 4; ++w) {
                float4 e = *(const float4*)&bc[buf][w][0];
                unsigned long long k2 =
                    ((unsigned long long)__float_as_uint(e.y) << 32) |
                    __float_as_uint(e.x);
                float z2 = bc[buf][w][4];
                bool take = (k2 > bk);
                bk = take ? k2 : bk;
                bx = take ? e.z : bx;
                by = take ? e.w : by;
                bz = take ? z2 : bz;
            }
            const int cur = (int)(~(unsigned)(bk & 0xFFFFFFFFull));
            cx = bx; cy = by; cz = bz;
            if (tid == 0)
                hist[s] = make_float4(__int_as_float(cur), bx, by, bz);
        }
        __syncthreads();
        // final publish [960,1024) + output drain
        if (tid < 192) {
            int cc = tid / 3, comp = tid % 3;
            float4 h = hist[960 + cc];
            float v = comp == 0 ? h.y : (comp == 1 ? h.z : h.w);
            __hip_atomic_store(
                (unsigned*)&histg[((size_t)(b * NS + 960 + cc)) * 3 + comp],
                __float_as_uint(v), __ATOMIC_RELAXED, __HIP_MEMORY_SCOPE_AGENT);
        }
        __syncthreads();
        if (tid == 0)
            __hip_atomic_store(&progress[b << 5], NS, __ATOMIC_RELEASE,
                               __HIP_MEMORY_SCOPE_AGENT);
        for (int s = tid; s < NS; s += 256) {
            float4 e = hist[s];
            out_pos[(size_t)(b * NS + s) * 3 + 0] = e.y;
            out_pos[(size_t)(b * NS + s) * 3 + 1] = e.z;
            out_pos[(size_t)(b * NS + s) * 3 + 2] = e.w;
            out_batch[b * NS + s] = (float)b;
        }
        return;
    }

    // ======================= consumer: ball + MFMA conv (R12) ===============
    const int w = blockIdx.x - NB;  // 0..239
    short* h1s = (short*)smem;                      // 8KB
    short* h2s = (short*)(smem + 8192);             // 8KB
    float* cd2 = (float*)(smem + 16384);            // [4][CAP]
    int*   cix = (int*)(smem + 18432);              // [4][CAP]
    float* dpxA = (float*)(smem + 20480);           // [4][64]
    float* dpyA = (float*)(smem + 21504);
    float* dpzA = (float*)(smem + 22528);
    int*   jA   = (int*)(smem + 23552);             // [4][64]
    float* omax = (float*)(smem + 24576);           // [4][128]
    int*   keepW = (int*)(smem + 26624);            // [4]
    const int lg = lane >> 4;
    const int lr = lane & 15;
    // ---- W fragments (bf16) into registers, once per block ----
    bf16x8 w1f[3][4], w2f[2][4], w3f[2][8];
#pragma unroll
    for (int kt = 0; kt < 3; ++kt)
#pragma unroll
        for (int ct = 0; ct < 4; ++ct) {
            bf16x8 f;
#pragma unroll
            for (int i = 0; i < 8; ++i) {
                int k = 32 * kt + 8 * lg + i;
                float v = (k < 67) ? W1[k * 64 + 16 * ct + lr] : 0.f;
                f[i] = f2bf(v);
            }
            w1f[kt][ct] = f;
        }
#pragma unroll
    for (int kt = 0; kt < 2; ++kt)
#pragma unroll
        for (int ct = 0; ct < 4; ++ct) {
            bf16x8 f;
#pragma unroll
            for (int i = 0; i < 8; ++i) {
                int k = 32 * kt + 8 * lg + i;
                f[i] = f2bf(W2[k * 64 + 16 * ct + lr]);
            }
            w2f[kt][ct] = f;
        }
#pragma unroll
    for (int kt = 0; kt < 2; ++kt)
#pragma unroll
        for (int ct = 0; ct < 8; ++ct) {
            bf16x8 f;
#pragma unroll
            for (int i = 0; i < 8; ++i) {
                int k = 32 * kt + 8 * lg + i;
                f[i] = f2bf(W3[k * 128 + 16 * ct + lr]);
            }
            w3f[kt][ct] = f;
        }
    float b1v[4], b2v[4], b3v[8];
#pragma unroll
    for (int ct = 0; ct < 4; ++ct) {
        b1v[ct] = b1[16 * ct + lr];
        b2v[ct] = b2[16 * ct + lr];
    }
#pragma unroll
    for (int ct = 0; ct < 8; ++ct) b3v[ct] = b3[16 * ct + lr];

    for (int c = w; c < NCHUNK; c += NCONS) {
        const int s = c >> 2;
        const int bq = (c & 3) << 2;
        const int bw = bq + wv;
        while (__hip_atomic_load(&progress[bw << 5], __ATOMIC_ACQUIRE,
                                 __HIP_MEMORY_SCOPE_AGENT) <= s) {
            __builtin_amdgcn_s_sleep(16);
        }
        const size_t ho = ((size_t)(bw * NS + s)) * 3;
        const float ccx = __uint_as_float(__hip_atomic_load(
            (const unsigned*)&histg[ho + 0], __ATOMIC_RELAXED,
            __HIP_MEMORY_SCOPE_AGENT));
        const float ccy = __uint_as_float(__hip_atomic_load(
            (const unsigned*)&histg[ho + 1], __ATOMIC_RELAXED,
            __HIP_MEMORY_SCOPE_AGENT));
        const float ccz = __uint_as_float(__hip_atomic_load(
            (const unsigned*)&histg[ho + 2], __ATOMIC_RELAXED,
            __HIP_MEMORY_SCOPE_AGENT));
        // ---- per-wave ball query ----
        int cnt = 0;
        const float* pcloud = pos + (size_t)bw * NP * 3;
        for (int it = 0; it < 64; ++it) {
            const int j = it * 64 + lane;
            const float* pp = pcloud + (size_t)j * 3;
            float d2 = dist2e(ccx, ccy, ccz, pp[0], pp[1], pp[2]);
            bool in = (d2 <= 0.01f);  // f32(0.1*0.1)
            unsigned long long m = __ballot(in);
            if (in) {
                int slot = cnt + __popcll(m & ((1ull << lane) - 1ull));
                if (slot < CAP) {
                    cd2[wv * CAP + slot] = d2;
                    cix[wv * CAP + slot] = j;
                }
            }
            cnt += __popcll(m);
        }
        if (cnt > CAP) cnt = CAP;
        const int keep = cnt <= KN ? cnt : KN;
        if (lane == 0) keepW[wv] = keep;
        jA[wv * 64 + lane] = 0;
        if (cnt <= KN) {
            if (lane < keep) jA[wv * 64 + lane] = cix[wv * CAP + lane];
        } else {
            // exact K-nearest: rank by (d2, idx) lexicographic (top_k order)
            for (int e = lane; e < cnt; e += 64) {
                float d = cd2[wv * CAP + e];
                int id = cix[wv * CAP + e];
                int rank = 0;
                for (int q = 0; q < cnt; ++q) {
                    float dq = cd2[wv * CAP + q];
                    int iq = cix[wv * CAP + q];
                    rank += (dq < d || (dq == d && iq < id)) ? 1 : 0;
                }
                if (rank < KN) jA[wv * 64 + rank] = id;
            }
        }
        {
            int j = jA[wv * 64 + lane];
            const float* pp = pcloud + (size_t)j * 3;
            bool valid = lane < keep;
            dpxA[wv * 64 + lane] = valid ? (pp[0] - ccx) : 0.f;
            dpyA[wv * 64 + lane] = valid ? (pp[1] - ccy) : 0.f;
            dpzA[wv * 64 + lane] = valid ? (pp[2] - ccz) : 0.f;
        }
        __syncthreads();
        // ---- conv for the 4 centers (R10 MFMA path) ----
        for (int cc = 0; cc < 4; ++cc) {
            const int C = keepW[cc];
            const int cen = (bq + cc) * NS + s;
            const int arow = 16 * wv + lr;
            bf16x8 a0, a1, a2;
            {
                const int jrow = (bq + cc) * NP + jA[cc * 64 + arow];
                const float* xr = x + (size_t)jrow * FIN + 8 * lg;
                float4 v0 = *(const float4*)(xr + 0);
                float4 v1 = *(const float4*)(xr + 4);
                float4 v2 = *(const float4*)(xr + 32);
                float4 v3 = *(const float4*)(xr + 36);
                a0[0] = f2bf(v0.x); a0[1] = f2bf(v0.y); a0[2] = f2bf(v0.z); a0[3] = f2bf(v0.w);
                a0[4] = f2bf(v1.x); a0[5] = f2bf(v1.y); a0[6] = f2bf(v1.z); a0[7] = f2bf(v1.w);
                a1[0] = f2bf(v2.x); a1[1] = f2bf(v2.y); a1[2] = f2bf(v2.z); a1[3] = f2bf(v2.w);
                a1[4] = f2bf(v3.x); a1[5] = f2bf(v3.y); a1[6] = f2bf(v3.z); a1[7] = f2bf(v3.w);
                float d0 = (lg == 0) ? dpxA[cc * 64 + arow] : 0.f;
                float d1 = (lg == 0) ? dpyA[cc * 64 + arow] : 0.f;
                float d2v = (lg == 0) ? dpzA[cc * 64 + arow] : 0.f;
                a2[0] = f2bf(d0); a2[1] = f2bf(d1); a2[2] = f2bf(d2v);
                a2[3] = 0; a2[4] = 0; a2[5] = 0; a2[6] = 0; a2[7] = 0;
            }
            {
                f32x4 acc[4];
#pragma unroll
                for (int ct = 0; ct < 4; ++ct) {
                    acc[ct] = (f32x4){b1v[ct], b1v[ct], b1v[ct], b1v[ct]};
                    acc[ct] = __builtin_amdgcn_mfma_f32_16x16x32_bf16(a0, w1f[0][ct], acc[ct], 0, 0, 0);
                    acc[ct] = __builtin_amdgcn_mfma_f32_16x16x32_bf16(a1, w1f[1][ct], acc[ct], 0, 0, 0);
                    acc[ct] = __builtin_amdgcn_mfma_f32_16x16x32_bf16(a2, w1f[2][ct], acc[ct], 0, 0, 0);
                }
#pragma unroll
                for (int ct = 0; ct < 4; ++ct)
#pragma unroll
                    for (int r = 0; r < 4; ++r) {
                        int rw = 16 * wv + 4 * lg + r;
                        int idx = rw * 64 + 16 * ct + lr;
                        h1s[idx ^ ((rw & 7) << 3)] = f2bf(fmaxf(acc[ct][r], 0.f));
                    }
            }
            bf16x8 ha0 = *(bf16x8*)&h1s[(arow * 64 + 0  + 8 * lg) ^ ((arow & 7) << 3)];
            bf16x8 ha1 = *(bf16x8*)&h1s[(arow * 64 + 32 + 8 * lg) ^ ((arow & 7) << 3)];
            {
                f32x4 acc[4];
#pragma unroll
                for (int ct = 0; ct < 4; ++ct) {
                    acc[ct] = (f32x4){b2v[ct], b2v[ct], b2v[ct], b2v[ct]};
                    acc[ct] = __builtin_amdgcn_mfma_f32_16x16x32_bf16(ha0, w2f[0][ct], acc[ct], 0, 0, 0);
                    acc[ct] = __builtin_amdgcn_mfma_f32_16x16x32_bf16(ha1, w2f[1][ct], acc[ct], 0, 0, 0);
                }
#pragma unroll
                for (int ct = 0; ct < 4; ++ct)
#pragma unroll
                    for (int r = 0; r < 4; ++r) {
                        int rw = 16 * wv + 4 * lg + r;
                        int idx = rw * 64 + 16 * ct + lr;
                        h2s[idx ^ ((rw & 7) << 3)] = f2bf(fmaxf(acc[ct][r], 0.f));
                    }
            }
            bf16x8 hb0 = *(bf16x8*)&h2s[(arow * 64 + 0  + 8 * lg) ^ ((arow & 7) << 3)];
            bf16x8 hb1 = *(bf16x8*)&h2s[(arow * 64 + 32 + 8 * lg) ^ ((arow & 7) << 3)];
            {
                f32x4 acc3[8];
#pragma unroll
                for (int ct = 0; ct < 8; ++ct) {
                    acc3[ct] = (f32x4){b3v[ct], b3v[ct], b3v[ct], b3v[ct]};
                    acc3[ct] = __builtin_amdgcn_mfma_f32_16x16x32_bf16(hb0, w3f[0][ct], acc3[ct], 0, 0, 0);
                    acc3[ct] = __builtin_amdgcn_mfma_f32_16x16x32_bf16(hb1, w3f[1][ct], acc3[ct], 0, 0, 0);
                }
#pragma unroll
                for (int ct = 0; ct < 8; ++ct) {
                    float m = -INFINITY;
#pragma unroll
                    for (int r = 0; r < 4; ++r) {
                        int rg = 16 * wv + 4 * lg + r;
                        float v = fmaxf(acc3[ct][r], 0.f);
                        m = (rg < C && v > m) ? v : m;
                    }
                    m = fmaxf(m, __shfl_xor(m, 16, 64));
                    m = fmaxf(m, __shfl_xor(m, 32, 64));
                    if (lg == 0) omax[wv * 128 + 16 * ct + lr] = m;
                }
            }
            __syncthreads();
            if (tid < 128) {
                float m = fmaxf(fmaxf(omax[0 * 128 + tid], omax[1 * 128 + tid]),
                                fmaxf(omax[2 * 128 + tid], omax[3 * 128 + tid]));
                out_feat[(size_t)cen * 128 + tid] = m;
            }
            __syncthreads();
        }
    }
}

extern "C" void kernel_launch(void* const* d_in, const int* in_sizes, int n_in,
                              void* d_out, int out_size, void* d_ws, size_t ws_size,
                              hipStream_t stream) {
    const float* x   = (const float*)d_in[0];
    const float* pos = (const float*)d_in[1];
    const float* W1  = (const float*)d_in[3];
    const float* b1  = (const float*)d_in[4];
    const float* W2  = (const float*)d_in[5];
    const float* b2  = (const float*)d_in[6];
    const float* W3  = (const float*)d_in[7];
    const float* b3  = (const float*)d_in[8];
    float* out = (float*)d_out;
    char* ws = (char*)d_ws;
    int*   progress = (int*)ws;                    // 16 x 128B padded slots
    float* histg    = (float*)(ws + 4096);         // [16][1024][3] = 192KB
    float* out_feat  = out;                        // [16384][128]
    float* out_pos   = out + (size_t)16384 * 128;  // [16384][3]
    float* out_batch = out + (size_t)16384 * 131;  // [16384]
    hipMemsetAsync(ws, 0, 4096, stream);
    fused_kernel<<<256, 256, 0, stream>>>(pos, x, W1, b1, W2, b2, W3, b3,
                                          out_feat, out_pos, out_batch,
                                          histg, progress);
}

// Round 17
// 913.571 us; speedup vs baseline: 1.1458x; 1.1048x over previous
//
#include <hip/hip_runtime.h>
#include <hip/hip_bf16.h>
#include <math.h>

// PointNet++ SAModule: FPS -> ball query -> PointNetConv(MLP, max-agg)
// B=16, N=4096, S=1024, K=64, r=0.1, MLP 67->64->64->128.
// R17 = R12 (best measured, 914us) + packed-f32 local loop in the producer:
// point-pair distance math via v_pk_add/mul_f32 (fp contract OFF -> bit-exact
// vs numpy: separate RN mul/add, same order), scalar min + scalar argmax scan
// in the same ascending order (selection bit-identical). Everything else
// (key-only 6-DPP u64 ladder, readlane bcast, winner-writes-bc, 64-step
// publish, padded progress, s_sleep spin, MFMA consumers) is R12 verbatim.

#define NB 16
#define NP 4096
#define FIN 64
#define NS 1024
#define KN 64
#define CAP 128
#define NCONS 240
#define NCHUNK 4096

typedef __attribute__((ext_vector_type(8))) short bf16x8;
typedef __attribute__((ext_vector_type(4))) float f32x4;
typedef __attribute__((ext_vector_type(2))) float f32x2;

__device__ __forceinline__ float dist2e(float ax, float ay, float az,
                                        float bx, float by, float bz) {
    float dx = __fsub_rn(ax, bx);
    float dy = __fsub_rn(ay, by);
    float dz = __fsub_rn(az, bz);
    return __fadd_rn(__fadd_rn(__fmul_rn(dx, dx), __fmul_rn(dy, dy)),
                     __fmul_rn(dz, dz));
}

__device__ __forceinline__ short f2bf(float f) {  // RNE fp32 -> bf16 bits
    unsigned u = __float_as_uint(f);
    unsigned r = (u + 0x7FFFu + ((u >> 16) & 1u)) >> 16;
    return (short)r;
}

#define DPP_KEY_MAX(k, CTRL)                                                   \
    do {                                                                       \
        int _lo = (int)(unsigned)((k) & 0xFFFFFFFFull);                        \
        int _hi = (int)(unsigned)((k) >> 32);                                  \
        int _plo = __builtin_amdgcn_update_dpp(_lo, _lo, CTRL, 0xF, 0xF, false);\
        int _phi = __builtin_amdgcn_update_dpp(_hi, _hi, CTRL, 0xF, 0xF, false);\
        unsigned long long _nk =                                               \
            ((unsigned long long)(unsigned)_phi << 32) | (unsigned)_plo;       \
        if (_nk > (k)) (k) = _nk;                                              \
    } while (0)

#define SMEM_BYTES 27648

__global__ __launch_bounds__(256, 1) void fused_kernel(
        const float* __restrict__ pos, const float* __restrict__ x,
        const float* __restrict__ W1, const float* __restrict__ b1,
        const float* __restrict__ W2, const float* __restrict__ b2,
        const float* __restrict__ W3, const float* __restrict__ b3,
        float* __restrict__ out_feat, float* __restrict__ out_pos,
        float* __restrict__ out_batch, float* __restrict__ histg,
        int* __restrict__ progress) {
    __shared__ __align__(16) char smem[SMEM_BYTES];
    const int tid = threadIdx.x;
    const int lane = tid & 63;
    const int wv = tid >> 6;

    if (blockIdx.x < NB) {
        // =================== FPS producer (R12 + packed local) ==============
        const int b = blockIdx.x;
        float4* hist = (float4*)smem;                       // [1024] 16KB
        float (*bc)[4][8] = (float(*)[4][8])(smem + 16384); // [2][4][8]
        const float* p = pos + (size_t)b * NP * 3;
        f32x2 lx2[8], ly2[8], lz2[8], md2[8];
#pragma unroll
        for (int k = 0; k < 8; ++k) {
#pragma unroll
            for (int e = 0; e < 2; ++e) {
                int j = tid + ((2 * k + e) << 8);
                lx2[k][e] = p[j * 3 + 0];
                ly2[k][e] = p[j * 3 + 1];
                lz2[k][e] = p[j * 3 + 2];
            }
            md2[k] = (f32x2){INFINITY, INFINITY};
        }
        const float c0x = p[0], c0y = p[1], c0z = p[2];
        float cx = c0x, cy = c0y, cz = c0z;
        if (tid == 0) hist[0] = make_float4(0.f, c0x, c0y, c0z);
        for (int s = 1; s < NS; ++s) {
            // packed md update: v_pk_add/mul (IEEE RN per element, no fma
            // contraction) -> identical bits to scalar __f*_rn sequence
            {
#pragma clang fp contract(off)
                const f32x2 cx2 = (f32x2){cx, cx};
                const f32x2 cy2 = (f32x2){cy, cy};
                const f32x2 cz2 = (f32x2){cz, cz};
#pragma unroll
                for (int k = 0; k < 8; ++k) {
                    f32x2 dx = lx2[k] - cx2;
                    f32x2 dy = ly2[k] - cy2;
                    f32x2 dz = lz2[k] - cz2;
                    f32x2 d = (dx * dx + dy * dy) + dz * dz;
                    f32x2 m = md2[k];
                    m[0] = d[0] < m[0] ? d[0] : m[0];  // jnp.minimum (exact)
                    m[1] = d[1] < m[1] ? d[1] : m[1];
                    md2[k] = m;
                }
            }
            // scalar argmax scan, ascending index, strict > (= np.argmax
            // first-occurrence), with xyz carry (R12 structure A)
            float bv = -1.0f;
            int bi = 0;
            float wx = 0.f, wy = 0.f, wz = 0.f;
#pragma unroll
            for (int k = 0; k < 8; ++k) {
#pragma unroll
                for (int e = 0; e < 2; ++e) {
                    float m = md2[k][e];
                    bool take = (m > bv);
                    bv = take ? m : bv;
                    bi = take ? (tid + ((2 * k + e) << 8)) : bi;
                    wx = take ? lx2[k][e] : wx;
                    wy = take ? ly2[k][e] : wy;
                    wz = take ? lz2[k][e] : wz;
                }
            }
            // pack: positive-f32 bits order-isomorphic; ~idx => tie->lower idx
            unsigned long long key =
                ((unsigned long long)__float_as_uint(bv) << 32) |
                (unsigned)(~(unsigned)bi);
            const unsigned long long my = key;
            DPP_KEY_MAX(key, 0x111);
            DPP_KEY_MAX(key, 0x112);
            DPP_KEY_MAX(key, 0x114);
            DPP_KEY_MAX(key, 0x118);
            DPP_KEY_MAX(key, 0x142);
            DPP_KEY_MAX(key, 0x143);
            const unsigned kwlo = (unsigned)__builtin_amdgcn_readlane(
                (int)(unsigned)(key & 0xFFFFFFFFull), 63);
            const unsigned kwhi = (unsigned)__builtin_amdgcn_readlane(
                (int)(unsigned)(key >> 32), 63);
            const unsigned long long kw =
                ((unsigned long long)kwhi << 32) | kwlo;
            const int buf = s & 1;
            if (my == kw) {            // unique winner lane (idx in key)
                bc[buf][wv][0] = __uint_as_float(kwlo);
                bc[buf][wv][1] = __uint_as_float(kwhi);
                bc[buf][wv][2] = wx;
                bc[buf][wv][3] = wy;
                bc[buf][wv][4] = wz;
            }
            __syncthreads();
            if ((s & 63) == 0) {   // publish centers [s-64, s)
                const int base = s - 64;
                if (tid < 192) {
                    int cc = tid / 3, comp = tid % 3;
                    float4 h = hist[base + cc];
                    float v = comp == 0 ? h.y : (comp == 1 ? h.z : h.w);
                    __hip_atomic_store(
                        (unsigned*)&histg[((size_t)(b * NS + base + cc)) * 3 + comp],
                        __float_as_uint(v), __ATOMIC_RELAXED,
                        __HIP_MEMORY_SCOPE_AGENT);
                }
                __syncthreads();   // drain stores before release
                if (tid == 0)
                    __hip_atomic_store(&progress[b << 5], s, __ATOMIC_RELEASE,
                                       __HIP_MEMORY_SCOPE_AGENT);
            }
            // all lanes: select best of the 4 wave candidates
            unsigned long long bk;
            float bx, by, bz;
            {
                float4 e = *(const float4*)&bc[buf][0][0];
                bk = ((unsigned long long)__float_as_uint(e.y) << 32) |
                     __float_as_uint(e.x);
                bx = e.z; by = e.w; bz = bc[buf][0][4];
            }
#pragma unroll
            for (int w = 1; w < 4; ++w) {
                float4 e = *(const float4*)&bc[buf][w][0];
                unsigned long long k2 =
                    ((unsigned long long)__float_as_uint(e.y) << 32) |
                    __float_as_uint(e.x);
                float z2 = bc[buf][w][4];
                bool take = (k2 > bk);
                bk = take ? k2 : bk;
                bx = take ? e.z : bx;
                by = take ? e.w : by;
                bz = take ? z2 : bz;
            }
            const int cur = (int)(~(unsigned)(bk & 0xFFFFFFFFull));
            cx = bx; cy = by; cz = bz;
            if (tid == 0)
                hist[s] = make_float4(__int_as_float(cur), bx, by, bz);
        }
        __syncthreads();
        // final publish [960,1024) + output drain
        if (tid < 192) {
            int cc = tid / 3, comp = tid % 3;
            float4 h = hist[960 + cc];
            float v = comp == 0 ? h.y : (comp == 1 ? h.z : h.w);
            __hip_atomic_store(
                (unsigned*)&histg[((size_t)(b * NS + 960 + cc)) * 3 + comp],
                __float_as_uint(v), __ATOMIC_RELAXED, __HIP_MEMORY_SCOPE_AGENT);
        }
        __syncthreads();
        if (tid == 0)
            __hip_atomic_store(&progress[b << 5], NS, __ATOMIC_RELEASE,
                               __HIP_MEMORY_SCOPE_AGENT);
        for (int s = tid; s < NS; s += 256) {
            float4 e = hist[s];
            out_pos[(size_t)(b * NS + s) * 3 + 0] = e.y;
            out_pos[(size_t)(b * NS + s) * 3 + 1] = e.z;
            out_pos[(size_t)(b * NS + s) * 3 + 2] = e.w;
            out_batch[b * NS + s] = (float)b;
        }
        return;
    }

    // ======================= consumer: ball + MFMA conv (R12) ===============
    const int w = blockIdx.x - NB;  // 0..239
    short* h1s = (short*)smem;                      // 8KB
    short* h2s = (short*)(smem + 8192);             // 8KB
    float* cd2 = (float*)(smem + 16384);            // [4][CAP]
    int*   cix = (int*)(smem + 18432);              // [4][CAP]
    float* dpxA = (float*)(smem + 20480);           // [4][64]
    float* dpyA = (float*)(smem + 21504);
    float* dpzA = (float*)(smem + 22528);
    int*   jA   = (int*)(smem + 23552);             // [4][64]
    float* omax = (float*)(smem + 24576);           // [4][128]
    int*   keepW = (int*)(smem + 26624);            // [4]
    const int lg = lane >> 4;
    const int lr = lane & 15;
    // ---- W fragments (bf16) into registers, once per block ----
    bf16x8 w1f[3][4], w2f[2][4], w3f[2][8];
#pragma unroll
    for (int kt = 0; kt < 3; ++kt)
#pragma unroll
        for (int ct = 0; ct < 4; ++ct) {
            bf16x8 f;
#pragma unroll
            for (int i = 0; i < 8; ++i) {
                int k = 32 * kt + 8 * lg + i;
                float v = (k < 67) ? W1[k * 64 + 16 * ct + lr] : 0.f;
                f[i] = f2bf(v);
            }
            w1f[kt][ct] = f;
        }
#pragma unroll
    for (int kt = 0; kt < 2; ++kt)
#pragma unroll
        for (int ct = 0; ct < 4; ++ct) {
            bf16x8 f;
#pragma unroll
            for (int i = 0; i < 8; ++i) {
                int k = 32 * kt + 8 * lg + i;
                f[i] = f2bf(W2[k * 64 + 16 * ct + lr]);
            }
            w2f[kt][ct] = f;
        }
#pragma unroll
    for (int kt = 0; kt < 2; ++kt)
#pragma unroll
        for (int ct = 0; ct < 8; ++ct) {
            bf16x8 f;
#pragma unroll
            for (int i = 0; i < 8; ++i) {
                int k = 32 * kt + 8 * lg + i;
                f[i] = f2bf(W3[k * 128 + 16 * ct + lr]);
            }
            w3f[kt][ct] = f;
        }
    float b1v[4], b2v[4], b3v[8];
#pragma unroll
    for (int ct = 0; ct < 4; ++ct) {
        b1v[ct] = b1[16 * ct + lr];
        b2v[ct] = b2[16 * ct + lr];
    }
#pragma unroll
    for (int ct = 0; ct < 8; ++ct) b3v[ct] = b3[16 * ct + lr];

    for (int c = w; c < NCHUNK; c += NCONS) {
        const int s = c >> 2;
        const int bq = (c & 3) << 2;
        const int bw = bq + wv;
        while (__hip_atomic_load(&progress[bw << 5], __ATOMIC_ACQUIRE,
                                 __HIP_MEMORY_SCOPE_AGENT) <= s) {
            __builtin_amdgcn_s_sleep(16);
        }
        const size_t ho = ((size_t)(bw * NS + s)) * 3;
        const float ccx = __uint_as_float(__hip_atomic_load(
            (const unsigned*)&histg[ho + 0], __ATOMIC_RELAXED,
            __HIP_MEMORY_SCOPE_AGENT));
        const float ccy = __uint_as_float(__hip_atomic_load(
            (const unsigned*)&histg[ho + 1], __ATOMIC_RELAXED,
            __HIP_MEMORY_SCOPE_AGENT));
        const float ccz = __uint_as_float(__hip_atomic_load(
            (const unsigned*)&histg[ho + 2], __ATOMIC_RELAXED,
            __HIP_MEMORY_SCOPE_AGENT));
        // ---- per-wave ball query ----
        int cnt = 0;
        const float* pcloud = pos + (size_t)bw * NP * 3;
        for (int it = 0; it < 64; ++it) {
            const int j = it * 64 + lane;
            const float* pp = pcloud + (size_t)j * 3;
            float d2 = dist2e(ccx, ccy, ccz, pp[0], pp[1], pp[2]);
            bool in = (d2 <= 0.01f);  // f32(0.1*0.1)
            unsigned long long m = __ballot(in);
            if (in) {
                int slot = cnt + __popcll(m & ((1ull << lane) - 1ull));
                if (slot < CAP) {
                    cd2[wv * CAP + slot] = d2;
                    cix[wv * CAP + slot] = j;
                }
            }
            cnt += __popcll(m);
        }
        if (cnt > CAP) cnt = CAP;
        const int keep = cnt <= KN ? cnt : KN;
        if (lane == 0) keepW[wv] = keep;
        jA[wv * 64 + lane] = 0;
        if (cnt <= KN) {
            if (lane < keep) jA[wv * 64 + lane] = cix[wv * CAP + lane];
        } else {
            // exact K-nearest: rank by (d2, idx) lexicographic (top_k order)
            for (int e = lane; e < cnt; e += 64) {
                float d = cd2[wv * CAP + e];
                int id = cix[wv * CAP + e];
                int rank = 0;
                for (int q = 0; q < cnt; ++q) {
                    float dq = cd2[wv * CAP + q];
                    int iq = cix[wv * CAP + q];
                    rank += (dq < d || (dq == d && iq < id)) ? 1 : 0;
                }
                if (rank < KN) jA[wv * 64 + rank] = id;
            }
        }
        {
            int j = jA[wv * 64 + lane];
            const float* pp = pcloud + (size_t)j * 3;
            bool valid = lane < keep;
            dpxA[wv * 64 + lane] = valid ? (pp[0] - ccx) : 0.f;
            dpyA[wv * 64 + lane] = valid ? (pp[1] - ccy) : 0.f;
            dpzA[wv * 64 + lane] = valid ? (pp[2] - ccz) : 0.f;
        }
        __syncthreads();
        // ---- conv for the 4 centers (R10 MFMA path) ----
        for (int cc = 0; cc < 4; ++cc) {
            const int C = keepW[cc];
            const int cen = (bq + cc) * NS + s;
            const int arow = 16 * wv + lr;
            bf16x8 a0, a1, a2;
            {
                const int jrow = (bq + cc) * NP + jA[cc * 64 + arow];
                const float* xr = x + (size_t)jrow * FIN + 8 * lg;
                float4 v0 = *(const float4*)(xr + 0);
                float4 v1 = *(const float4*)(xr + 4);
                float4 v2 = *(const float4*)(xr + 32);
                float4 v3 = *(const float4*)(xr + 36);
                a0[0] = f2bf(v0.x); a0[1] = f2bf(v0.y); a0[2] = f2bf(v0.z); a0[3] = f2bf(v0.w);
                a0[4] = f2bf(v1.x); a0[5] = f2bf(v1.y); a0[6] = f2bf(v1.z); a0[7] = f2bf(v1.w);
                a1[0] = f2bf(v2.x); a1[1] = f2bf(v2.y); a1[2] = f2bf(v2.z); a1[3] = f2bf(v2.w);
                a1[4] = f2bf(v3.x); a1[5] = f2bf(v3.y); a1[6] = f2bf(v3.z); a1[7] = f2bf(v3.w);
                float d0 = (lg == 0) ? dpxA[cc * 64 + arow] : 0.f;
                float d1 = (lg == 0) ? dpyA[cc * 64 + arow] : 0.f;
                float d2v = (lg == 0) ? dpzA[cc * 64 + arow] : 0.f;
                a2[0] = f2bf(d0); a2[1] = f2bf(d1); a2[2] = f2bf(d2v);
                a2[3] = 0; a2[4] = 0; a2[5] = 0; a2[6] = 0; a2[7] = 0;
            }
            {
                f32x4 acc[4];
#pragma unroll
                for (int ct = 0; ct < 4; ++ct) {
                    acc[ct] = (f32x4){b1v[ct], b1v[ct], b1v[ct], b1v[ct]};
                    acc[ct] = __builtin_amdgcn_mfma_f32_16x16x32_bf16(a0, w1f[0][ct], acc[ct], 0, 0, 0);
                    acc[ct] = __builtin_amdgcn_mfma_f32_16x16x32_bf16(a1, w1f[1][ct], acc[ct], 0, 0, 0);
                    acc[ct] = __builtin_amdgcn_mfma_f32_16x16x32_bf16(a2, w1f[2][ct], acc[ct], 0, 0, 0);
                }
#pragma unroll
                for (int ct = 0; ct < 4; ++ct)
#pragma unroll
                    for (int r = 0; r < 4; ++r) {
                        int rw = 16 * wv + 4 * lg + r;
                        int idx = rw * 64 + 16 * ct + lr;
                        h1s[idx ^ ((rw & 7) << 3)] = f2bf(fmaxf(acc[ct][r], 0.f));
                    }
            }
            bf16x8 ha0 = *(bf16x8*)&h1s[(arow * 64 + 0  + 8 * lg) ^ ((arow & 7) << 3)];
            bf16x8 ha1 = *(bf16x8*)&h1s[(arow * 64 + 32 + 8 * lg) ^ ((arow & 7) << 3)];
            {
                f32x4 acc[4];
#pragma unroll
                for (int ct = 0; ct < 4; ++ct) {
                    acc[ct] = (f32x4){b2v[ct], b2v[ct], b2v[ct], b2v[ct]};
                    acc[ct] = __builtin_amdgcn_mfma_f32_16x16x32_bf16(ha0, w2f[0][ct], acc[ct], 0, 0, 0);
                    acc[ct] = __builtin_amdgcn_mfma_f32_16x16x32_bf16(ha1, w2f[1][ct], acc[ct], 0, 0, 0);
                }
#pragma unroll
                for (int ct = 0; ct < 4; ++ct)
#pragma unroll
                    for (int r = 0; r < 4; ++r) {
                        int rw = 16 * wv + 4 * lg + r;
                        int idx = rw * 64 + 16 * ct + lr;
                        h2s[idx ^ ((rw & 7) << 3)] = f2bf(fmaxf(acc[ct][r], 0.f));
                    }
            }
            bf16x8 hb0 = *(bf16x8*)&h2s[(arow * 64 + 0  + 8 * lg) ^ ((arow & 7) << 3)];
            bf16x8 hb1 = *(bf16x8*)&h2s[(arow * 64 + 32 + 8 * lg) ^ ((arow & 7) << 3)];
            {
                f32x4 acc3[8];
#pragma unroll
                for (int ct = 0; ct < 8; ++ct) {
                    acc3[ct] = (f32x4){b3v[ct], b3v[ct], b3v[ct], b3v[ct]};
                    acc3[ct] = __builtin_amdgcn_mfma_f32_16x16x32_bf16(hb0, w3f[0][ct], acc3[ct], 0, 0, 0);
                    acc3[ct] = __builtin_amdgcn_mfma_f32_16x16x32_bf16(hb1, w3f[1][ct], acc3[ct], 0, 0, 0);
                }
#pragma unroll
                for (int ct = 0; ct < 8; ++ct) {
                    float m = -INFINITY;
#pragma unroll
                    for (int r = 0; r < 4; ++r) {
                        int rg = 16 * wv + 4 * lg + r;
                        float v = fmaxf(acc3[ct][r], 0.f);
                        m = (rg < C && v > m) ? v : m;
                    }
                    m = fmaxf(m, __shfl_xor(m, 16, 64));
                    m = fmaxf(m, __shfl_xor(m, 32, 64));
                    if (lg == 0) omax[wv * 128 + 16 * ct + lr] = m;
                }
            }
            __syncthreads();
            if (tid < 128) {
                float m = fmaxf(fmaxf(omax[0 * 128 + tid], omax[1 * 128 + tid]),
                                fmaxf(omax[2 * 128 + tid], omax[3 * 128 + tid]));
                out_feat[(size_t)cen * 128 + tid] = m;
            }
            __syncthreads();
        }
    }
}

extern "C" void kernel_launch(void* const* d_in, const int* in_sizes, int n_in,
                              void* d_out, int out_size, void* d_ws, size_t ws_size,
                              hipStream_t stream) {
    const float* x   = (const float*)d_in[0];
    const float* pos = (const float*)d_in[1];
    const float* W1  = (const float*)d_in[3];
    const float* b1  = (const float*)d_in[4];
    const float* W2  = (const float*)d_in[5];
    const float* b2  = (const float*)d_in[6];
    const float* W3  = (const float*)d_in[7];
    const float* b3  = (const float*)d_in[8];
    float* out = (float*)d_out;
    char* ws = (char*)d_ws;
    int*   progress = (int*)ws;                    // 16 x 128B padded slots
    float* histg    = (float*)(ws + 4096);         // [16][1024][3] = 192KB
    float* out_feat  = out;                        // [16384][128]
    float* out_pos   = out + (size_t)16384 * 128;  // [16384][3]
    float* out_batch = out + (size_t)16384 * 131;  // [16384]
    hipMemsetAsync(ws, 0, 4096, stream);
    fused_kernel<<<256, 256, 0, stream>>>(pos, x, W1, b1, W2, b2, W3, b3,
                                          out_feat, out_pos, out_batch,
                                          histg, progress);
}